// Round 1
// baseline (126.688 us; speedup 1.0000x reference)
//
#include <hip/hip_runtime.h>

#define H 512
#define V 50000

__device__ __forceinline__ float sigmoidf(float x) {
    return 1.0f / (1.0f + __expf(-x));
}

__device__ __forceinline__ float wave_reduce(float v) {
    #pragma unroll
    for (int m = 32; m >= 1; m >>= 1)
        v += __shfl_xor(v, m, 64);
    return v;
}

__device__ __forceinline__ float dot4(float4 a, float4 b) {
    return a.x * b.x + a.y * b.y + a.z * b.z + a.w * b.w;
}

// Kernel A: h3_new -> out[V+H .. V+H+512), tmp = x_emb@Wx.T + Bx + b_ictx -> ws
// 256 blocks x 256 threads: waves 0,1 do W_h3 rows 2b,2b+1; waves 2,3 do Wx rows.
__global__ __launch_bounds__(256) void kA(
    const int* __restrict__ inputX, const float* __restrict__ intervalX,
    const float* __restrict__ h3, const float* __restrict__ emb,
    const float* __restrict__ W_h3, const float* __restrict__ b_h3,
    const float* __restrict__ W_int, const float* __restrict__ b_int,
    const float* __restrict__ Wx, const float* __restrict__ Bx,
    const float* __restrict__ b_ictx,
    float* __restrict__ out, float* __restrict__ tmp)
{
    const int tid  = threadIdx.x;
    const int wv   = tid >> 6;
    const int lane = tid & 63;
    const int r    = blockIdx.x * 2 + (wv & 1);
    const bool doWx = (wv >= 2);

    const float* vec  = doWx ? (emb + (size_t)inputX[0] * H) : h3;
    const float* Wrow = (doWx ? Wx : W_h3) + (size_t)r * H;
    const float4* W4 = (const float4*)Wrow;
    const float4* v4 = (const float4*)vec;

    float4 a0 = W4[lane],      a1 = W4[64 + lane];
    float4 x0 = v4[lane],      x1 = v4[64 + lane];
    float p = dot4(a0, x0) + dot4(a1, x1);
    p = wave_reduce(p);

    if (lane == 0) {
        if (doWx) {
            tmp[r] = p + Bx[r] + b_ictx[r];
        } else {
            float pre = p + intervalX[0] * W_int[r] + b_int[r] + b_h3[r];
            out[V + H + r] = sigmoidf(pre);
        }
    }
}

// Kernel B: fused hypernet + gated update.
// block j computes h_new[j] = sigmoid(tmp[j] + sum_k h[k]*sigmoid(dot(h3n, W_ctx[j*512+k,:]) + b_ctx[j*512+k]))
// 512 blocks x 1024 threads (16 waves): wave w handles rows k = w*32 .. w*32+31.
__global__ __launch_bounds__(1024) void kB(
    const float* __restrict__ h, const float* __restrict__ W_ctx,
    const float* __restrict__ b_ctx, const float* __restrict__ h3n,
    const float* __restrict__ tmp, float* __restrict__ out)
{
    __shared__ float sh3[H];
    __shared__ float sh[H];
    __shared__ float red[16];

    const int tid = threadIdx.x;
    if (tid < H) sh3[tid] = h3n[tid];
    else         sh[tid - H] = h[tid - H];
    __syncthreads();

    const int wv   = tid >> 6;
    const int lane = tid & 63;
    const int j    = blockIdx.x;

    const float4* s3 = (const float4*)sh3;
    const float4 x0 = s3[lane];
    const float4 x1 = s3[64 + lane];

    const size_t base = (size_t)j * H;
    float acc = 0.0f;

    #pragma unroll 4
    for (int i = 0; i < 32; ++i) {
        const int k = wv * 32 + i;
        const float4* W4 = (const float4*)(W_ctx + (base + (size_t)k) * H);
        float4 a0 = W4[lane];
        float4 a1 = W4[64 + lane];
        float p = dot4(a0, x0) + dot4(a1, x1);
        p = wave_reduce(p);
        float s = p + b_ctx[base + (size_t)k];
        acc += sh[k] * sigmoidf(s);
    }

    if (lane == 0) red[wv] = acc;
    __syncthreads();

    if (tid == 0) {
        float t = tmp[j];
        #pragma unroll
        for (int w = 0; w < 16; ++w) t += red[w];
        out[V + j] = sigmoidf(t);
    }
}

// Kernel C: logits = h_new @ fc_W.T + fc_b.
// 3125 blocks x 256 threads: block handles 16 rows, wave w rows 16b+4w .. +3.
__global__ __launch_bounds__(256) void kC(
    const float* __restrict__ h_new, const float* __restrict__ fc_W,
    const float* __restrict__ fc_b, float* __restrict__ out)
{
    __shared__ float shn[H];
    const int tid = threadIdx.x;
    shn[tid]       = h_new[tid];
    shn[tid + 256] = h_new[tid + 256];
    __syncthreads();

    const int wv   = tid >> 6;
    const int lane = tid & 63;
    const float4* s4 = (const float4*)shn;
    const float4 x0 = s4[lane];
    const float4 x1 = s4[64 + lane];

    const int rbase = blockIdx.x * 16 + wv * 4;
    #pragma unroll
    for (int r = 0; r < 4; ++r) {
        const int v = rbase + r;
        const float4* W4 = (const float4*)(fc_W + (size_t)v * H);
        float4 a0 = W4[lane];
        float4 a1 = W4[64 + lane];
        float p = dot4(a0, x0) + dot4(a1, x1);
        p = wave_reduce(p);
        if (lane == 0) out[v] = p + fc_b[v];
    }
}

extern "C" void kernel_launch(void* const* d_in, const int* in_sizes, int n_in,
                              void* d_out, int out_size, void* d_ws, size_t ws_size,
                              hipStream_t stream) {
    const int*   inputX    = (const int*)d_in[0];
    // d_in[1] hourX, d_in[2] weekdayX: unused by reference
    const float* intervalX = (const float*)d_in[3];
    const float* h         = (const float*)d_in[4];
    const float* h3        = (const float*)d_in[5];
    const float* emb       = (const float*)d_in[6];
    const float* W_h3      = (const float*)d_in[7];
    const float* b_h3      = (const float*)d_in[8];
    const float* W_int     = (const float*)d_in[9];
    const float* b_int     = (const float*)d_in[10];
    const float* W_ctx     = (const float*)d_in[11];
    const float* b_ctx     = (const float*)d_in[12];
    const float* b_ictx    = (const float*)d_in[13];
    const float* Wx        = (const float*)d_in[14];
    const float* Bx        = (const float*)d_in[15];
    const float* fc_W      = (const float*)d_in[16];
    const float* fc_b      = (const float*)d_in[17];

    float* out = (float*)d_out;          // [logits(50000) | h_new(512) | h3_new(512)]
    float* tmp = (float*)d_ws;           // 512 floats: x_emb@Wx.T + Bx + b_ictx

    kA<<<256, 256, 0, stream>>>(inputX, intervalX, h3, emb, W_h3, b_h3,
                                W_int, b_int, Wx, Bx, b_ictx, out, tmp);
    kB<<<512, 1024, 0, stream>>>(h, W_ctx, b_ctx, out + V + H, tmp, out);
    kC<<<3125, 256, 0, stream>>>(out + V, fc_W, fc_b, out);
}

// Round 3
// 113.460 us; speedup vs baseline: 1.1166x; 1.1166x over previous
//
#include <hip/hip_runtime.h>

#define H 512
#define V 50000

typedef float fx4 __attribute__((ext_vector_type(4)));

__device__ __forceinline__ float sigmoidf(float x) {
    return 1.0f / (1.0f + __expf(-x));
}

__device__ __forceinline__ float wave_reduce(float v) {
    #pragma unroll
    for (int m = 32; m >= 1; m >>= 1)
        v += __shfl_xor(v, m, 64);
    return v;
}

__device__ __forceinline__ float dot4(fx4 a, fx4 b) {
    return a.x * b.x + a.y * b.y + a.z * b.z + a.w * b.w;
}

__device__ __forceinline__ fx4 ntload4(const float* p) {
    return __builtin_nontemporal_load((const fx4*)p);
}

__device__ __forceinline__ fx4 ld4(const float* p) {
    return *(const fx4*)p;
}

// Kernel A: h3_new only. 256 blocks x 128 threads (2 waves), wave handles one row.
__global__ __launch_bounds__(128) void kA(
    const float* __restrict__ intervalX, const float* __restrict__ h3,
    const float* __restrict__ W_h3, const float* __restrict__ b_h3,
    const float* __restrict__ W_int, const float* __restrict__ b_int,
    float* __restrict__ out)
{
    const int tid  = threadIdx.x;
    const int wv   = tid >> 6;
    const int lane = tid & 63;
    const int r    = blockIdx.x * 2 + wv;

    const float* Wrow = W_h3 + (size_t)r * H;
    fx4 a0 = ntload4(Wrow + lane * 4);
    fx4 a1 = ntload4(Wrow + 256 + lane * 4);
    fx4 x0 = ld4(h3 + lane * 4);
    fx4 x1 = ld4(h3 + 256 + lane * 4);
    float p = dot4(a0, x0) + dot4(a1, x1);
    p = wave_reduce(p);

    if (lane == 0) {
        float pre = p + intervalX[0] * W_int[r] + b_int[r] + b_h3[r];
        out[V + H + r] = sigmoidf(pre);
    }
}

// Kernel B: fused hypernet + gated update (+ folded x_emb@Wx.T term).
// block j: h_new[j] = sigmoid( dot(x_emb,Wx[j]) + Bx[j] + b_ictx[j]
//                              + sum_k h[k]*sigmoid(dot(h3n, W_ctx[j*512+k,:]) + b_ctx[j*512+k]) )
// 512 blocks x 1024 threads (16 waves): wave w handles rows k = w*32 .. w*32+31.
__global__ __launch_bounds__(1024) void kB(
    const int* __restrict__ inputX, const float* __restrict__ emb,
    const float* __restrict__ h, const float* __restrict__ W_ctx,
    const float* __restrict__ b_ctx, const float* __restrict__ h3n,
    const float* __restrict__ Wx, const float* __restrict__ Bx,
    const float* __restrict__ b_ictx, float* __restrict__ out)
{
    __shared__ float sh3[H];
    __shared__ float sh[H];
    __shared__ float semb[H];
    __shared__ float sbc[H];
    __shared__ float red[16];

    const int tid = threadIdx.x;
    const int j   = blockIdx.x;
    const size_t base = (size_t)j * H;

    const float* embrow = emb + (size_t)inputX[0] * H;
    if (tid < H) {
        sh3[tid]  = h3n[tid];
        semb[tid] = embrow[tid];
    } else {
        const int t = tid - H;
        sh[t]  = h[t];
        sbc[t] = b_ctx[base + t];
    }
    __syncthreads();

    const int wv   = tid >> 6;
    const int lane = tid & 63;

    const fx4 x0 = ld4(sh3 + lane * 4);
    const fx4 x1 = ld4(sh3 + 256 + lane * 4);

    float acc = 0.0f;

    if (wv == 0) {
        // folded interaction-input term: dot(x_emb, Wx[j,:]) + Bx[j] + b_ictx[j]
        const float* Wxrow = Wx + (size_t)j * H;
        fx4 a0 = ntload4(Wxrow + lane * 4);
        fx4 a1 = ntload4(Wxrow + 256 + lane * 4);
        float p = dot4(a0, ld4(semb + lane * 4)) + dot4(a1, ld4(semb + 256 + lane * 4));
        p = wave_reduce(p);
        acc += p + Bx[j] + b_ictx[j];   // same on all lanes; only lane0's red used
    }

    #pragma unroll 4
    for (int i = 0; i < 32; ++i) {
        const int k = wv * 32 + i;
        const float* Wrow = W_ctx + (base + (size_t)k) * H;
        fx4 a0 = ntload4(Wrow + lane * 4);
        fx4 a1 = ntload4(Wrow + 256 + lane * 4);
        float p = dot4(a0, x0) + dot4(a1, x1);
        p = wave_reduce(p);
        float s = p + sbc[k];
        acc += sh[k] * sigmoidf(s);
    }

    if (lane == 0) red[wv] = acc;
    __syncthreads();

    if (tid == 0) {
        float t = 0.0f;
        #pragma unroll
        for (int w = 0; w < 16; ++w) t += red[w];
        out[V + j] = sigmoidf(t);
    }
}

// Kernel C: logits = h_new @ fc_W.T + fc_b.
// 3125 blocks x 256 threads: block handles 16 rows, wave w rows 16b+4w .. +3.
__global__ __launch_bounds__(256) void kC(
    const float* __restrict__ h_new, const float* __restrict__ fc_W,
    const float* __restrict__ fc_b, float* __restrict__ out)
{
    __shared__ float shn[H];
    const int tid = threadIdx.x;
    shn[tid]       = h_new[tid];
    shn[tid + 256] = h_new[tid + 256];
    __syncthreads();

    const int wv   = tid >> 6;
    const int lane = tid & 63;
    const fx4 x0 = ld4(shn + lane * 4);
    const fx4 x1 = ld4(shn + 256 + lane * 4);

    const int rbase = blockIdx.x * 16 + wv * 4;
    #pragma unroll
    for (int r = 0; r < 4; ++r) {
        const int v = rbase + r;
        const float* Wrow = fc_W + (size_t)v * H;
        fx4 a0 = ntload4(Wrow + lane * 4);
        fx4 a1 = ntload4(Wrow + 256 + lane * 4);
        float p = dot4(a0, x0) + dot4(a1, x1);
        p = wave_reduce(p);
        if (lane == 0) out[v] = p + fc_b[v];
    }
}

extern "C" void kernel_launch(void* const* d_in, const int* in_sizes, int n_in,
                              void* d_out, int out_size, void* d_ws, size_t ws_size,
                              hipStream_t stream) {
    const int*   inputX    = (const int*)d_in[0];
    const float* intervalX = (const float*)d_in[3];
    const float* h         = (const float*)d_in[4];
    const float* h3        = (const float*)d_in[5];
    const float* emb       = (const float*)d_in[6];
    const float* W_h3      = (const float*)d_in[7];
    const float* b_h3      = (const float*)d_in[8];
    const float* W_int     = (const float*)d_in[9];
    const float* b_int     = (const float*)d_in[10];
    const float* W_ctx     = (const float*)d_in[11];
    const float* b_ctx     = (const float*)d_in[12];
    const float* b_ictx    = (const float*)d_in[13];
    const float* Wx        = (const float*)d_in[14];
    const float* Bx        = (const float*)d_in[15];
    const float* fc_W      = (const float*)d_in[16];
    const float* fc_b      = (const float*)d_in[17];

    float* out = (float*)d_out;          // [logits(50000) | h_new(512) | h3_new(512)]

    kA<<<256, 128, 0, stream>>>(intervalX, h3, W_h3, b_h3, W_int, b_int, out);
    kB<<<512, 1024, 0, stream>>>(inputX, emb, h, W_ctx, b_ctx, out + V + H,
                                 Wx, Bx, b_ictx, out);
    kC<<<3125, 256, 0, stream>>>(out + V, fc_W, fc_b, out);
}

// Round 4
// 108.484 us; speedup vs baseline: 1.1678x; 1.0459x over previous
//
#include <hip/hip_runtime.h>

#define H 512
#define V 50000

typedef float fx4 __attribute__((ext_vector_type(4)));

__device__ __forceinline__ float sigmoidf(float x) {
    return 1.0f / (1.0f + __expf(-x));
}

__device__ __forceinline__ float wave_reduce(float v) {
    #pragma unroll
    for (int m = 32; m >= 1; m >>= 1)
        v += __shfl_xor(v, m, 64);
    return v;
}

__device__ __forceinline__ float dot4(fx4 a, fx4 b) {
    return a.x * b.x + a.y * b.y + a.z * b.z + a.w * b.w;
}

__device__ __forceinline__ fx4 ntload4(const float* p) {
    return __builtin_nontemporal_load((const fx4*)p);
}

__device__ __forceinline__ fx4 ld4(const float* p) {
    return *(const fx4*)p;
}

// Kernel A: h3_new only. 256 blocks x 128 threads (2 waves), wave handles one row.
// Plain loads: W_h3 (1MB) stays LLC-resident across graph replays.
__global__ __launch_bounds__(128) void kA(
    const float* __restrict__ intervalX, const float* __restrict__ h3,
    const float* __restrict__ W_h3, const float* __restrict__ b_h3,
    const float* __restrict__ W_int, const float* __restrict__ b_int,
    float* __restrict__ out)
{
    const int tid  = threadIdx.x;
    const int wv   = tid >> 6;
    const int lane = tid & 63;
    const int r    = blockIdx.x * 2 + wv;

    const float* Wrow = W_h3 + (size_t)r * H;
    fx4 a0 = ld4(Wrow + lane * 4);
    fx4 a1 = ld4(Wrow + 256 + lane * 4);
    fx4 x0 = ld4(h3 + lane * 4);
    fx4 x1 = ld4(h3 + 256 + lane * 4);
    float p = dot4(a0, x0) + dot4(a1, x1);
    p = wave_reduce(p);

    if (lane == 0) {
        float pre = p + intervalX[0] * W_int[r] + b_int[r] + b_h3[r];
        out[V + H + r] = sigmoidf(pre);
    }
}

// Kernel B: fused hypernet + gated update (+ folded x_emb@Wx.T term).
// block j: h_new[j] = sigmoid( dot(x_emb,Wx[j]) + Bx[j] + b_ictx[j]
//                              + sum_k h[k]*sigmoid(dot(h3n, W_ctx[j*512+k,:]) + b_ctx[j*512+k]) )
// 512 blocks x 1024 threads (16 waves): wave w handles rows k = w*32 .. w*32+31.
// LLC strategy: blocks with (j&3)==0 use plain loads (128MB of W_ctx kept
// resident across replays); the rest use nt (evict-first) loads.
__global__ __launch_bounds__(1024) void kB(
    const int* __restrict__ inputX, const float* __restrict__ emb,
    const float* __restrict__ h, const float* __restrict__ W_ctx,
    const float* __restrict__ b_ctx, const float* __restrict__ h3n,
    const float* __restrict__ Wx, const float* __restrict__ Bx,
    const float* __restrict__ b_ictx, float* __restrict__ out)
{
    __shared__ float sh3[H];
    __shared__ float sh[H];
    __shared__ float semb[H];
    __shared__ float sbc[H];
    __shared__ float red[16];

    const int tid = threadIdx.x;
    const int j   = blockIdx.x;
    const size_t base = (size_t)j * H;

    const float* embrow = emb + (size_t)inputX[0] * H;
    if (tid < H) {
        sh3[tid]  = h3n[tid];
        semb[tid] = embrow[tid];
    } else {
        const int t = tid - H;
        sh[t]  = h[t];
        sbc[t] = b_ctx[base + t];
    }
    __syncthreads();

    const int wv   = tid >> 6;
    const int lane = tid & 63;

    const fx4 x0 = ld4(sh3 + lane * 4);
    const fx4 x1 = ld4(sh3 + 256 + lane * 4);

    float acc = 0.0f;

    if (wv == 0) {
        // folded interaction-input term: dot(x_emb, Wx[j,:]) + Bx[j] + b_ictx[j]
        const float* Wxrow = Wx + (size_t)j * H;
        fx4 a0 = ld4(Wxrow + lane * 4);
        fx4 a1 = ld4(Wxrow + 256 + lane * 4);
        float p = dot4(a0, ld4(semb + lane * 4)) + dot4(a1, ld4(semb + 256 + lane * 4));
        p = wave_reduce(p);
        acc += p + Bx[j] + b_ictx[j];   // same on all lanes; only lane0's red used
    }

    if ((j & 3) == 0) {
        // LLC-resident quarter: plain loads
        #pragma unroll 4
        for (int i = 0; i < 32; ++i) {
            const int k = wv * 32 + i;
            const float* Wrow = W_ctx + (base + (size_t)k) * H;
            fx4 a0 = ld4(Wrow + lane * 4);
            fx4 a1 = ld4(Wrow + 256 + lane * 4);
            float p = dot4(a0, x0) + dot4(a1, x1);
            p = wave_reduce(p);
            acc += sh[k] * sigmoidf(p + sbc[k]);
        }
    } else {
        // streaming three-quarters: nt (evict-first) loads
        #pragma unroll 4
        for (int i = 0; i < 32; ++i) {
            const int k = wv * 32 + i;
            const float* Wrow = W_ctx + (base + (size_t)k) * H;
            fx4 a0 = ntload4(Wrow + lane * 4);
            fx4 a1 = ntload4(Wrow + 256 + lane * 4);
            float p = dot4(a0, x0) + dot4(a1, x1);
            p = wave_reduce(p);
            acc += sh[k] * sigmoidf(p + sbc[k]);
        }
    }

    if (lane == 0) red[wv] = acc;
    __syncthreads();

    if (tid == 0) {
        float t = 0.0f;
        #pragma unroll
        for (int w = 0; w < 16; ++w) t += red[w];
        out[V + j] = sigmoidf(t);
    }
}

// Kernel C: logits = h_new @ fc_W.T + fc_b.
// 3125 blocks x 256 threads: block handles 16 rows, wave w rows 16b+4w .. +3.
// Plain loads: fc_W (100MB) stays LLC-resident across graph replays.
__global__ __launch_bounds__(256) void kC(
    const float* __restrict__ h_new, const float* __restrict__ fc_W,
    const float* __restrict__ fc_b, float* __restrict__ out)
{
    __shared__ float shn[H];
    const int tid = threadIdx.x;
    shn[tid]       = h_new[tid];
    shn[tid + 256] = h_new[tid + 256];
    __syncthreads();

    const int wv   = tid >> 6;
    const int lane = tid & 63;
    const fx4 x0 = ld4(shn + lane * 4);
    const fx4 x1 = ld4(shn + 256 + lane * 4);

    const int rbase = blockIdx.x * 16 + wv * 4;
    #pragma unroll
    for (int r = 0; r < 4; ++r) {
        const int v = rbase + r;
        const float* Wrow = fc_W + (size_t)v * H;
        fx4 a0 = ld4(Wrow + lane * 4);
        fx4 a1 = ld4(Wrow + 256 + lane * 4);
        float p = dot4(a0, x0) + dot4(a1, x1);
        p = wave_reduce(p);
        if (lane == 0) out[v] = p + fc_b[v];
    }
}

extern "C" void kernel_launch(void* const* d_in, const int* in_sizes, int n_in,
                              void* d_out, int out_size, void* d_ws, size_t ws_size,
                              hipStream_t stream) {
    const int*   inputX    = (const int*)d_in[0];
    const float* intervalX = (const float*)d_in[3];
    const float* h         = (const float*)d_in[4];
    const float* h3        = (const float*)d_in[5];
    const float* emb       = (const float*)d_in[6];
    const float* W_h3      = (const float*)d_in[7];
    const float* b_h3      = (const float*)d_in[8];
    const float* W_int     = (const float*)d_in[9];
    const float* b_int     = (const float*)d_in[10];
    const float* W_ctx     = (const float*)d_in[11];
    const float* b_ctx     = (const float*)d_in[12];
    const float* b_ictx    = (const float*)d_in[13];
    const float* Wx        = (const float*)d_in[14];
    const float* Bx        = (const float*)d_in[15];
    const float* fc_W      = (const float*)d_in[16];
    const float* fc_b      = (const float*)d_in[17];

    float* out = (float*)d_out;          // [logits(50000) | h_new(512) | h3_new(512)]

    kA<<<256, 128, 0, stream>>>(intervalX, h3, W_h3, b_h3, W_int, b_int, out);
    kB<<<512, 1024, 0, stream>>>(inputX, emb, h, W_ctx, b_ctx, out + V + H,
                                 Wx, Bx, b_ictx, out);
    kC<<<3125, 256, 0, stream>>>(out + V, fc_W, fc_b, out);
}